// Round 2
// baseline (332.748 us; speedup 1.0000x reference)
//
#include <hip/hip_runtime.h>
#include <cstdint>
#include <cstddef>

typedef __bf16 bf16;
typedef __attribute__((ext_vector_type(8))) __bf16 bf16x8;
typedef __attribute__((ext_vector_type(4))) __bf16 bf16x4;
typedef __attribute__((ext_vector_type(4))) float f32x4;

#define ADIM 1024
#define ASEQ 2048
#define ABATCH 8

__device__ __forceinline__ void gload_lds16(const void* g, void* l) {
  __builtin_amdgcn_global_load_lds(
      (const __attribute__((address_space(1))) void*)g,
      (__attribute__((address_space(3))) void*)l,
      16, 0, 0);
}

__device__ __forceinline__ f32x4 mfma16(bf16x8 a, bf16x8 b, f32x4 c) {
  return __builtin_amdgcn_mfma_f32_16x16x32_bf16(a, b, c, 0, 0, 0);
}

// ---------------- cast x (fp32 -> bf16), vectorized ----------------
__global__ void k_cast_x(const float* __restrict__ x, bf16* __restrict__ xb, int n4) {
  int i = blockIdx.x * blockDim.x + threadIdx.x;
  int stride = gridDim.x * blockDim.x;
  for (; i < n4; i += stride) {
    float4 f = ((const float4*)x)[i];
    bf16x4 o = { (bf16)f.x, (bf16)f.y, (bf16)f.z, (bf16)f.w };
    ((bf16x4*)xb)[i] = o;
  }
}

// ------------- weights: cast + transpose into B^T form -------------
__global__ void k_prep_w(const float* __restrict__ Wq, const float* __restrict__ Wk,
                         const float* __restrict__ Wv, const float* __restrict__ Wo,
                         bf16* __restrict__ WcT, bf16* __restrict__ WoT) {
  int i = blockIdx.x * blockDim.x + threadIdx.x;
  int stride = gridDim.x * blockDim.x;
  const int NC = 3 * ADIM * ADIM;
  const int TOT = 4 * ADIM * ADIM;
  for (; i < TOT; i += stride) {
    if (i < NC) {
      int n = i >> 10, k = i & 1023;
      int cb = n >> 10, nn = n & 1023;
      const float* W = (cb == 0) ? Wq : (cb == 1) ? Wk : Wv;
      WcT[i] = (bf16)W[k * ADIM + nn];
    } else {
      int j = i - NC;
      int n = j >> 10, k = j & 1023;
      WoT[j] = (bf16)Wo[k * ADIM + n];
    }
  }
}

// ========== 256x256-tile BK=32 GEMM, 4-slot LDS ring, counted vmcnt ==========
// C[m][n] = sum_k A[m][k] * BT[n][k];  512 threads = 8 waves (2 M x 4 N).
// LDS layout per slot: addr16(kg,row) = kg*256 + row  (kg = k-octet 0..3).
// Stage writes linearly (global_load_lds lane x 16B); the (kg,row) permutation
// is applied on the per-lane GLOBAL source address (both-sides rule).
// MODE 0: N=3072 fused QKV epilogue; MODE 1: fp32 out + bias.
template<int MODE>
__global__ __launch_bounds__(512, 2) void k_gemm256(
    const bf16* __restrict__ A, const bf16* __restrict__ BT,
    const float* __restrict__ bias0, const float* __restrict__ bias1,
    const float* __restrict__ bias2,
    bf16* __restrict__ Qo, bf16* __restrict__ Ko, bf16* __restrict__ Vto,
    float* __restrict__ outF, int M, int N, int K, int ntn)
{
  // XCD-aware swizzle (grid multiple of 8)
  const int nwg = gridDim.x;
  const int cpx = nwg >> 3;
  const int flat = blockIdx.x;
  const int sw = (flat & 7) * cpx + (flat >> 3);
  const int bx = sw % ntn, by = sw / ntn;
  const int m0 = by * 256, n0 = bx * 256;

  const int tid = threadIdx.x;
  const int l = tid & 63, w = tid >> 6;
  const int wm = w >> 2, wn = w & 3;
  const int lr = l & 15, kg = l >> 4;

  __shared__ alignas(16) bf16 sA[4][256 * 32];
  __shared__ alignas(16) bf16 sB[4][256 * 32];

  f32x4 acc[8][4] = {};
  const int KT = K >> 5;

  auto stage = [&](int slot, int kt) {
#pragma unroll
    for (int c = 0; c < 2; ++c) {
      const int chunk = w * 128 + c * 64 + l;       // lane-contiguous
      const int row = chunk & 255, g = chunk >> 8;  // LDS perm on SOURCE addr
      gload_lds16(A + (size_t)(m0 + row) * K + kt * 32 + g * 8,
                  &sA[slot][(w * 128 + c * 64) * 8]);
      gload_lds16(BT + (size_t)(n0 + row) * K + kt * 32 + g * 8,
                  &sB[slot][(w * 128 + c * 64) * 8]);
    }
  };

  // prologue: 3 tiles in flight
  stage(0, 0);
  if (KT > 1) stage(1, 1);
  if (KT > 2) stage(2, 2);

  int offA[8], offB[4];
#pragma unroll
  for (int i = 0; i < 8; ++i) offA[i] = (kg * 256 + wm * 128 + i * 16 + lr) * 8;
#pragma unroll
  for (int j = 0; j < 4; ++j) offB[j] = (kg * 256 + wn * 64 + j * 16 + lr) * 8;

  for (int t = 0; t < KT; ++t) {
    const int slot = t & 3;
    if (t + 2 < KT)      asm volatile("s_waitcnt vmcnt(8)" ::: "memory");
    else if (t + 1 < KT) asm volatile("s_waitcnt vmcnt(4)" ::: "memory");
    else                 asm volatile("s_waitcnt vmcnt(0)" ::: "memory");
    __builtin_amdgcn_s_barrier();
    asm volatile("" ::: "memory");

    if (t + 3 < KT) stage((t + 3) & 3, t + 3);

    bf16x8 af[8], bfr[4];
#pragma unroll
    for (int j = 0; j < 4; ++j) bfr[j] = *(const bf16x8*)&sB[slot][offB[j]];
#pragma unroll
    for (int i = 0; i < 8; ++i) af[i] = *(const bf16x8*)&sA[slot][offA[i]];

    __builtin_amdgcn_s_setprio(1);
#pragma unroll
    for (int i = 0; i < 8; ++i)
#pragma unroll
      for (int j = 0; j < 4; ++j)
        acc[i][j] = mfma16(af[i], bfr[j], acc[i][j]);
    __builtin_amdgcn_s_setprio(0);
  }

  // ---- epilogue ----
#pragma unroll
  for (int i = 0; i < 8; ++i) {
#pragma unroll
    for (int j = 0; j < 4; ++j) {
      const int n = n0 + wn * 64 + j * 16 + lr;
      const int m0r = m0 + wm * 128 + i * 16 + kg * 4;
      if (MODE == 0) {
        const int cb = n >> 10, nn = n & 1023;
        if (cb == 0) {
          const float b_ = bias0[nn];
#pragma unroll
          for (int r = 0; r < 4; ++r)
            Qo[(size_t)(m0r + r) * ADIM + nn] = (bf16)(acc[i][j][r] + b_);
        } else if (cb == 1) {
          const float b_ = bias1[nn];
#pragma unroll
          for (int r = 0; r < 4; ++r) {
            float v = acc[i][j][r] + b_;
            Ko[(size_t)(m0r + r) * ADIM + nn] = (bf16)(v > 0.f ? v + 1.f : __expf(v));
          }
        } else {
          const float b_ = bias2[nn];
          const int bb = m0r >> 11, t0c = m0r & 2047;   // 256-tile never crosses batch
          bf16x4 pk;
#pragma unroll
          for (int r = 0; r < 4; ++r) pk[r] = (bf16)(acc[i][j][r] + b_);
          *(bf16x4*)&Vto[((size_t)bb * ADIM + nn) * ASEQ + t0c] = pk;
        }
      } else {
        const float b_ = bias0[n];
#pragma unroll
        for (int r = 0; r < 4; ++r)
          outF[(size_t)(m0r + r) * N + n] = acc[i][j][r] + b_;
      }
    }
  }
}

// --------- windowed decay attention: one (batch, 64-row q-tile) per WG ---------
__global__ __launch_bounds__(256) void k_attn(
    const bf16* __restrict__ Qg, const bf16* __restrict__ Kg,
    const bf16* __restrict__ Vt, bf16* __restrict__ Rb,
    const float* __restrict__ decay_param)
{
  const int b = blockIdx.y;
  const int T0 = blockIdx.x * 64;
  const int tid = threadIdx.x;
  const int l = tid & 63, w = tid >> 6;
  const int lr = l & 15, lk = (l >> 4) * 8;

  const float dp = decay_param[0];
  const float decay = 1.f / (1.f + __expf(-dp));
  const float l2d = __log2f(decay);

  __shared__ alignas(16) bf16 lQ[2][64 * 32];
  __shared__ alignas(16) bf16 lK[2][128 * 32];
  __shared__ alignas(16) bf16 lV[2][128 * 32];
  __shared__ alignas(16) bf16 lP[64 * 136];

  const bf16* Qb = Qg + (size_t)(b * ASEQ + T0) * ADIM;

  auto stageQK = [&](int buf, int k0) {
    {
      const bf16* g = Qb + (size_t)(w * 16 + (l >> 2)) * ADIM + k0 + (l & 3) * 8;
      gload_lds16(g, &lQ[buf][w * 16 * 32]);
    }
#pragma unroll
    for (int cc = 0; cc < 2; ++cc) {
      int c = 2 * w + cc;
      int sg = T0 - 64 + c * 16 + (l >> 2);
      if (sg < 0) sg = 0;
      const bf16* g = Kg + (size_t)(b * ASEQ + sg) * ADIM + k0 + (l & 3) * 8;
      gload_lds16(g, &lK[buf][c * 16 * 32]);
    }
  };

  f32x4 sc[4][2] = {};
  stageQK(0, 0);
  __syncthreads();
  for (int kt = 0; kt < 32; ++kt) {
    int cur = kt & 1;
    if (kt + 1 < 32) stageQK(cur ^ 1, (kt + 1) * 32);
    bf16x8 af[4], bfr[2];
#pragma unroll
    for (int i = 0; i < 4; ++i)
      af[i] = *(const bf16x8*)&lQ[cur][(i * 16 + lr) * 32 + lk];
#pragma unroll
    for (int j = 0; j < 2; ++j)
      bfr[j] = *(const bf16x8*)&lK[cur][(w * 32 + j * 16 + lr) * 32 + lk];
#pragma unroll
    for (int i = 0; i < 4; ++i)
#pragma unroll
      for (int j = 0; j < 2; ++j)
        sc[i][j] = mfma16(af[i], bfr[j], sc[i][j]);
    __syncthreads();
  }

  const int er = (l >> 4) * 4, ec = l & 15;
#pragma unroll
  for (int i = 0; i < 4; ++i)
#pragma unroll
    for (int j = 0; j < 2; ++j)
#pragma unroll
      for (int r = 0; r < 4; ++r) {
        int tl = i * 16 + er + r;
        int sl = w * 32 + j * 16 + ec;
        int sg = T0 - 64 + sl;
        int delta = (T0 + tl) - 1 - sg;
        float wgt = (delta >= 0 && delta < 64 && sg >= 0)
                        ? exp2f((float)delta * l2d) : 0.f;
        lP[tl * 136 + sl] = (bf16)(sc[i][j][r] * wgt);
      }

  auto stageV = [&](int buf, int g) {
    int nc = g >> 2, ks = g & 3;
#pragma unroll
    for (int cc = 0; cc < 2; ++cc) {
      int c = 2 * w + cc;
      int drow = nc * 128 + c * 16 + (l >> 2);
      int scol = T0 - 64 + ks * 32 + (l & 3) * 8;
      if (scol < 0) scol = 0;
      const bf16* gv = Vt + ((size_t)b * ADIM + drow) * ASEQ + scol;
      gload_lds16(gv, &lV[buf][c * 16 * 32]);
    }
  };

  f32x4 o[4][2] = {};
  stageV(0, 0);
  __syncthreads();

  for (int g = 0; g < 32; ++g) {
    int cur = g & 1;
    if (g + 1 < 32) stageV(cur ^ 1, g + 1);
    int nc = g >> 2, ks = g & 3;
    bf16x8 af[4], bfr[2];
#pragma unroll
    for (int i = 0; i < 4; ++i)
      af[i] = *(const bf16x8*)&lP[(i * 16 + lr) * 136 + ks * 32 + lk];
#pragma unroll
    for (int j = 0; j < 2; ++j)
      bfr[j] = *(const bf16x8*)&lV[cur][(w * 32 + j * 16 + lr) * 32 + lk];
#pragma unroll
    for (int i = 0; i < 4; ++i)
#pragma unroll
      for (int j = 0; j < 2; ++j)
        o[i][j] = mfma16(af[i], bfr[j], o[i][j]);
    if (ks == 3) {
#pragma unroll
      for (int i = 0; i < 4; ++i)
#pragma unroll
        for (int j = 0; j < 2; ++j) {
#pragma unroll
          for (int r = 0; r < 4; ++r) {
            int tl = i * 16 + er + r;
            int dl = nc * 128 + w * 32 + j * 16 + ec;
            Rb[(size_t)(b * ASEQ + T0 + tl) * ADIM + dl] = (bf16)o[i][j][r];
          }
#pragma unroll
          for (int r = 0; r < 4; ++r) o[i][j][r] = 0.f;
        }
    }
    __syncthreads();
  }
}

extern "C" void kernel_launch(void* const* d_in, const int* in_sizes, int n_in,
                              void* d_out, int out_size, void* d_ws, size_t ws_size,
                              hipStream_t stream) {
  const float* x  = (const float*)d_in[0];
  const float* Wq = (const float*)d_in[1];
  const float* bq = (const float*)d_in[2];
  const float* Wk = (const float*)d_in[3];
  const float* bk = (const float*)d_in[4];
  const float* Wv = (const float*)d_in[5];
  const float* bv = (const float*)d_in[6];
  const float* Wo = (const float*)d_in[7];
  const float* bo = (const float*)d_in[8];
  const float* dp = (const float*)d_in[9];
  float* out = (float*)d_out;

  char* ws = (char*)d_ws;
  bf16* Xb  = (bf16*)(ws + ((size_t)0 << 20));    // [16384][1024]
  bf16* Qb  = (bf16*)(ws + ((size_t)32 << 20));
  bf16* Kb  = (bf16*)(ws + ((size_t)64 << 20));
  bf16* Vtb = (bf16*)(ws + ((size_t)96 << 20));   // [8][1024][2048]
  bf16* Rbb = (bf16*)(ws + ((size_t)128 << 20));
  bf16* WcT = (bf16*)(ws + ((size_t)160 << 20));  // [3072][1024]
  bf16* WoT = (bf16*)(ws + ((size_t)166 << 20));  // [1024][1024]

  const int M = ABATCH * ASEQ;  // 16384

  k_cast_x<<<2048, 256, 0, stream>>>(x, Xb, (M * ADIM) / 4);
  k_prep_w<<<2048, 256, 0, stream>>>(Wq, Wk, Wv, Wo, WcT, WoT);
  k_gemm256<0><<<768, 512, 0, stream>>>(
      Xb, WcT, bq, bk, bv, Qb, Kb, Vtb, nullptr, M, 3 * ADIM, ADIM, 12);
  k_attn<<<dim3(32, 8), 256, 0, stream>>>(Qb, Kb, Vtb, Rbb, dp);
  k_gemm256<1><<<256, 512, 0, stream>>>(
      Rbb, WoT, bo, nullptr, nullptr, nullptr, nullptr, nullptr, out, M, ADIM, ADIM, 4);
}

// Round 3
// 275.834 us; speedup vs baseline: 1.2063x; 1.2063x over previous
//
#include <hip/hip_runtime.h>
#include <cstdint>
#include <cstddef>

typedef __bf16 bf16;
typedef __attribute__((ext_vector_type(8))) __bf16 bf16x8;
typedef __attribute__((ext_vector_type(4))) __bf16 bf16x4;
typedef __attribute__((ext_vector_type(4))) float f32x4;

#define ADIM 1024
#define ASEQ 2048
#define ABATCH 8

__device__ __forceinline__ void gload_lds16(const void* g, void* l) {
  __builtin_amdgcn_global_load_lds(
      (const __attribute__((address_space(1))) void*)g,
      (__attribute__((address_space(3))) void*)l,
      16, 0, 0);
}

__device__ __forceinline__ f32x4 mfma16(bf16x8 a, bf16x8 b, f32x4 c) {
  return __builtin_amdgcn_mfma_f32_16x16x32_bf16(a, b, c, 0, 0, 0);
}

// ---------------- cast x (fp32 -> bf16), vectorized ----------------
__global__ void k_cast_x(const float* __restrict__ x, bf16* __restrict__ xb, int n4) {
  int i = blockIdx.x * blockDim.x + threadIdx.x;
  int stride = gridDim.x * blockDim.x;
  for (; i < n4; i += stride) {
    float4 f = ((const float4*)x)[i];
    bf16x4 o = { (bf16)f.x, (bf16)f.y, (bf16)f.z, (bf16)f.w };
    ((bf16x4*)xb)[i] = o;
  }
}

// ------------- weights: cast + transpose into B^T form -------------
__global__ void k_prep_w(const float* __restrict__ Wq, const float* __restrict__ Wk,
                         const float* __restrict__ Wv, const float* __restrict__ Wo,
                         bf16* __restrict__ WcT, bf16* __restrict__ WoT) {
  int i = blockIdx.x * blockDim.x + threadIdx.x;
  int stride = gridDim.x * blockDim.x;
  const int NC = 3 * ADIM * ADIM;
  const int TOT = 4 * ADIM * ADIM;
  for (; i < TOT; i += stride) {
    if (i < NC) {
      int n = i >> 10, k = i & 1023;
      int cb = n >> 10, nn = n & 1023;
      const float* W = (cb == 0) ? Wq : (cb == 1) ? Wk : Wv;
      WcT[i] = (bf16)W[k * ADIM + nn];
    } else {
      int j = i - NC;
      int n = j >> 10, k = j & 1023;
      WoT[j] = (bf16)Wo[k * ADIM + n];
    }
  }
}

// ====== 256x128-tile BK=64 GEMM, 3-slot LDS tile ring, 2 phases/K-step ======
// C[m][n] = sum_k A[m][k] * BT[n][k];  512 threads = 8 waves (4 M x 2 N).
// Per K-step t: consume slot t%3, prefetch tile t+2 into slot (t+2)%3.
// Per-wave vmcnt ledger: 6 gloads/step; vmcnt(6) at step end => tile t+1
// resident entering step t+1 (ring distance 2; never drains to 0 mid-loop).
// LDS st_16x32-style swizzle: col16' = col16 ^ ((row>>2&1)<<1), applied on
// the per-lane GLOBAL source (linear gload_lds dest) and on ds_read offsets.
// MODE 0: fused QKV epilogue (block's n-range lies in one of Q/K/V since
// 128 | 1024); MODE 1: fp32 out + bias.
template<int MODE>
__global__ __launch_bounds__(512, 2) void k_gemm8p(
    const bf16* __restrict__ A, const bf16* __restrict__ BT,
    const float* __restrict__ bias0, const float* __restrict__ bias1,
    const float* __restrict__ bias2,
    bf16* __restrict__ Qo, bf16* __restrict__ Ko, bf16* __restrict__ Vto,
    float* __restrict__ outF, int ntn)
{
  constexpr int K = 1024;
  constexpr int KT = K / 64;   // 16
  const int nwg = gridDim.x;
  const int cpx = nwg >> 3;
  const int flat = blockIdx.x;
  const int sw = (flat & 7) * cpx + (flat >> 3);   // grid % 8 == 0 (bijective)
  const int bx = sw % ntn, by = sw / ntn;
  const int m0 = by * 256, n0 = bx * 128;

  const int tid = threadIdx.x;
  const int l = tid & 63, w = tid >> 6;
  const int wm = w >> 1, wn = w & 1;
  const int lr = l & 15, kg = l >> 4;

  __shared__ alignas(16) bf16 sA[3][256 * 64];   // 96 KiB
  __shared__ alignas(16) bf16 sB[3][128 * 64];   // 48 KiB

  f32x4 acc[4][4] = {};

  // precomputed swizzled ds_read byte offsets
  int oA[4][2], oB[2][2][2];
#pragma unroll
  for (int i = 0; i < 4; ++i)
#pragma unroll
    for (int ks = 0; ks < 2; ++ks) {
      int r = wm * 64 + i * 16 + lr;
      int c16 = (ks * 4 + kg) ^ (((r >> 2) & 1) << 1);
      oA[i][ks] = (r * 8 + c16) * 16;
    }
#pragma unroll
  for (int h = 0; h < 2; ++h)
#pragma unroll
    for (int j = 0; j < 2; ++j)
#pragma unroll
      for (int ks = 0; ks < 2; ++ks) {
        int r = wn * 64 + h * 32 + j * 16 + lr;
        int c16 = (ks * 4 + kg) ^ (((r >> 2) & 1) << 1);
        oB[h][j][ks] = (r * 8 + c16) * 16;
      }

  auto stageA = [&](int sp, int kt2, int c) {
    int u = c * 512 + tid;
    int prow = u >> 3, pc = u & 7;
    int lc = pc ^ (((prow >> 2) & 1) << 1);       // inverse swizzle on source
    gload_lds16(A + (size_t)(m0 + prow) * K + kt2 * 64 + lc * 8,
                &sA[sp][(c * 512 + w * 64) * 8]);
  };
  auto stageB = [&](int sp, int kt2, int c) {
    int u = c * 512 + tid;
    int prow = u >> 3, pc = u & 7;
    int lc = pc ^ (((prow >> 2) & 1) << 1);
    gload_lds16(BT + (size_t)(n0 + prow) * K + kt2 * 64 + lc * 8,
                &sB[sp][(c * 512 + w * 64) * 8]);
  };

  // prologue: tiles 0 and 1 (12 gloads/thread), then require tile 0 resident
#pragma unroll
  for (int tt = 0; tt < 2; ++tt) {
    stageA(tt, tt, 0); stageA(tt, tt, 1); stageA(tt, tt, 2); stageA(tt, tt, 3);
    stageB(tt, tt, 0); stageB(tt, tt, 1);
  }
  asm volatile("s_waitcnt vmcnt(6)" ::: "memory");
  __builtin_amdgcn_s_barrier();
  asm volatile("" ::: "memory");

  for (int t = 0; t < KT; ++t) {
    const int s = t % 3, sp = (t + 2) % 3;
    const int tpc = (t + 2 < KT) ? t + 2 : t;    // dummy re-stage: uniform ledger
    const char* bA = (const char*)&sA[s][0];
    const char* bB = (const char*)&sB[s][0];

    // ---------------- phase 0: cols 0..31 ----------------
    bf16x8 af[4][2], b0[2][2];
#pragma unroll
    for (int i = 0; i < 4; ++i)
#pragma unroll
      for (int ks = 0; ks < 2; ++ks)
        af[i][ks] = *(const bf16x8*)(bA + oA[i][ks]);
#pragma unroll
    for (int j = 0; j < 2; ++j)
#pragma unroll
      for (int ks = 0; ks < 2; ++ks)
        b0[j][ks] = *(const bf16x8*)(bB + oB[0][j][ks]);
    stageA(sp, tpc, 0); stageA(sp, tpc, 1); stageB(sp, tpc, 0);
    asm volatile("" ::: "memory");
    __builtin_amdgcn_s_barrier();
    asm volatile("" ::: "memory");
    __builtin_amdgcn_s_setprio(1);
#pragma unroll
    for (int i = 0; i < 4; ++i)
#pragma unroll
      for (int j = 0; j < 2; ++j)
#pragma unroll
        for (int ks = 0; ks < 2; ++ks)
          acc[i][j] = mfma16(af[i][ks], b0[j][ks], acc[i][j]);
    __builtin_amdgcn_s_setprio(0);
    asm volatile("" ::: "memory");
    __builtin_amdgcn_s_barrier();
    asm volatile("" ::: "memory");

    // ---------------- phase 1: cols 32..63 ----------------
    bf16x8 b1[2][2];
#pragma unroll
    for (int j = 0; j < 2; ++j)
#pragma unroll
      for (int ks = 0; ks < 2; ++ks)
        b1[j][ks] = *(const bf16x8*)(bB + oB[1][j][ks]);
    stageA(sp, tpc, 2); stageA(sp, tpc, 3); stageB(sp, tpc, 1);
    asm volatile("" ::: "memory");
    __builtin_amdgcn_s_barrier();
    asm volatile("" ::: "memory");
    __builtin_amdgcn_s_setprio(1);
#pragma unroll
    for (int i = 0; i < 4; ++i)
#pragma unroll
      for (int j = 0; j < 2; ++j)
#pragma unroll
        for (int ks = 0; ks < 2; ++ks)
          acc[i][2 + j] = mfma16(af[i][ks], b1[j][ks], acc[i][2 + j]);
    __builtin_amdgcn_s_setprio(0);
    asm volatile("s_waitcnt vmcnt(6)" ::: "memory");   // tile t+1 now resident
    __builtin_amdgcn_s_barrier();
    asm volatile("" ::: "memory");
  }
  asm volatile("s_waitcnt vmcnt(0)" ::: "memory");     // drain tail dummies

  // ---- epilogue ----
  const int cb = n0 >> 10;          // uniform per block (128 | 1024)
#pragma unroll
  for (int i = 0; i < 4; ++i) {
#pragma unroll
    for (int jj = 0; jj < 4; ++jj) {
      const int n = n0 + wn * 64 + jj * 16 + lr;
      const int m0r = m0 + wm * 64 + i * 16 + kg * 4;
      if (MODE == 0) {
        const int nn = n & 1023;
        if (cb == 0) {
          const float b_ = bias0[nn];
#pragma unroll
          for (int r = 0; r < 4; ++r)
            Qo[(size_t)(m0r + r) * ADIM + nn] = (bf16)(acc[i][jj][r] + b_);
        } else if (cb == 1) {
          const float b_ = bias1[nn];
#pragma unroll
          for (int r = 0; r < 4; ++r) {
            float v = acc[i][jj][r] + b_;
            Ko[(size_t)(m0r + r) * ADIM + nn] = (bf16)(v > 0.f ? v + 1.f : __expf(v));
          }
        } else {
          const float b_ = bias2[nn];
          const int bb = m0r >> 11, t0c = m0r & 2047;
          bf16x4 pk;
#pragma unroll
          for (int r = 0; r < 4; ++r) pk[r] = (bf16)(acc[i][jj][r] + b_);
          *(bf16x4*)&Vto[((size_t)bb * ADIM + nn) * ASEQ + t0c] = pk;
        }
      } else {
        const float b_ = bias0[n];
#pragma unroll
        for (int r = 0; r < 4; ++r)
          outF[(size_t)(m0r + r) * ADIM + n] = acc[i][jj][r] + b_;
      }
    }
  }
}

// --------- windowed decay attention: one (batch, 64-row q-tile) per WG ---------
__global__ __launch_bounds__(256) void k_attn(
    const bf16* __restrict__ Qg, const bf16* __restrict__ Kg,
    const bf16* __restrict__ Vt, bf16* __restrict__ Rb,
    const float* __restrict__ decay_param)
{
  const int b = blockIdx.y;
  const int T0 = blockIdx.x * 64;
  const int tid = threadIdx.x;
  const int l = tid & 63, w = tid >> 6;
  const int lr = l & 15, lk = (l >> 4) * 8;

  const float dp = decay_param[0];
  const float decay = 1.f / (1.f + __expf(-dp));
  const float l2d = __log2f(decay);

  __shared__ alignas(16) bf16 lQ[2][64 * 32];
  __shared__ alignas(16) bf16 lK[2][128 * 32];
  __shared__ alignas(16) bf16 lV[2][128 * 32];
  __shared__ alignas(16) bf16 lP[64 * 136];

  const bf16* Qb = Qg + (size_t)(b * ASEQ + T0) * ADIM;

  auto stageQK = [&](int buf, int k0) {
    {
      const bf16* g = Qb + (size_t)(w * 16 + (l >> 2)) * ADIM + k0 + (l & 3) * 8;
      gload_lds16(g, &lQ[buf][w * 16 * 32]);
    }
#pragma unroll
    for (int cc = 0; cc < 2; ++cc) {
      int c = 2 * w + cc;
      int sg = T0 - 64 + c * 16 + (l >> 2);
      if (sg < 0) sg = 0;
      const bf16* g = Kg + (size_t)(b * ASEQ + sg) * ADIM + k0 + (l & 3) * 8;
      gload_lds16(g, &lK[buf][c * 16 * 32]);
    }
  };

  f32x4 sc[4][2] = {};
  stageQK(0, 0);
  __syncthreads();
  for (int kt = 0; kt < 32; ++kt) {
    int cur = kt & 1;
    if (kt + 1 < 32) stageQK(cur ^ 1, (kt + 1) * 32);
    bf16x8 af[4], bfr[2];
#pragma unroll
    for (int i = 0; i < 4; ++i)
      af[i] = *(const bf16x8*)&lQ[cur][(i * 16 + lr) * 32 + lk];
#pragma unroll
    for (int j = 0; j < 2; ++j)
      bfr[j] = *(const bf16x8*)&lK[cur][(w * 32 + j * 16 + lr) * 32 + lk];
#pragma unroll
    for (int i = 0; i < 4; ++i)
#pragma unroll
      for (int j = 0; j < 2; ++j)
        sc[i][j] = mfma16(af[i], bfr[j], sc[i][j]);
    __syncthreads();
  }

  const int er = (l >> 4) * 4, ec = l & 15;
#pragma unroll
  for (int i = 0; i < 4; ++i)
#pragma unroll
    for (int j = 0; j < 2; ++j)
#pragma unroll
      for (int r = 0; r < 4; ++r) {
        int tl = i * 16 + er + r;
        int sl = w * 32 + j * 16 + ec;
        int sg = T0 - 64 + sl;
        int delta = (T0 + tl) - 1 - sg;
        float wgt = (delta >= 0 && delta < 64 && sg >= 0)
                        ? exp2f((float)delta * l2d) : 0.f;
        lP[tl * 136 + sl] = (bf16)(sc[i][j][r] * wgt);
      }

  auto stageV = [&](int buf, int g) {
    int nc = g >> 2, ks = g & 3;
#pragma unroll
    for (int cc = 0; cc < 2; ++cc) {
      int c = 2 * w + cc;
      int drow = nc * 128 + c * 16 + (l >> 2);
      int scol = T0 - 64 + ks * 32 + (l & 3) * 8;
      if (scol < 0) scol = 0;
      const bf16* gv = Vt + ((size_t)b * ADIM + drow) * ASEQ + scol;
      gload_lds16(gv, &lV[buf][c * 16 * 32]);
    }
  };

  f32x4 o[4][2] = {};
  stageV(0, 0);
  __syncthreads();

  for (int g = 0; g < 32; ++g) {
    int cur = g & 1;
    if (g + 1 < 32) stageV(cur ^ 1, g + 1);
    int nc = g >> 2, ks = g & 3;
    bf16x8 af[4], bfr[2];
#pragma unroll
    for (int i = 0; i < 4; ++i)
      af[i] = *(const bf16x8*)&lP[(i * 16 + lr) * 136 + ks * 32 + lk];
#pragma unroll
    for (int j = 0; j < 2; ++j)
      bfr[j] = *(const bf16x8*)&lV[cur][(w * 32 + j * 16 + lr) * 32 + lk];
#pragma unroll
    for (int i = 0; i < 4; ++i)
#pragma unroll
      for (int j = 0; j < 2; ++j)
        o[i][j] = mfma16(af[i], bfr[j], o[i][j]);
    if (ks == 3) {
#pragma unroll
      for (int i = 0; i < 4; ++i)
#pragma unroll
        for (int j = 0; j < 2; ++j) {
#pragma unroll
          for (int r = 0; r < 4; ++r) {
            int tl = i * 16 + er + r;
            int dl = nc * 128 + w * 32 + j * 16 + ec;
            Rb[(size_t)(b * ASEQ + T0 + tl) * ADIM + dl] = (bf16)o[i][j][r];
          }
#pragma unroll
          for (int r = 0; r < 4; ++r) o[i][j][r] = 0.f;
        }
    }
    __syncthreads();
  }
}

extern "C" void kernel_launch(void* const* d_in, const int* in_sizes, int n_in,
                              void* d_out, int out_size, void* d_ws, size_t ws_size,
                              hipStream_t stream) {
  const float* x  = (const float*)d_in[0];
  const float* Wq = (const float*)d_in[1];
  const float* bq = (const float*)d_in[2];
  const float* Wk = (const float*)d_in[3];
  const float* bk = (const float*)d_in[4];
  const float* Wv = (const float*)d_in[5];
  const float* bv = (const float*)d_in[6];
  const float* Wo = (const float*)d_in[7];
  const float* bo = (const float*)d_in[8];
  const float* dp = (const float*)d_in[9];
  float* out = (float*)d_out;

  char* ws = (char*)d_ws;
  bf16* Xb  = (bf16*)(ws + ((size_t)0 << 20));    // [16384][1024]
  bf16* Qb  = (bf16*)(ws + ((size_t)32 << 20));
  bf16* Kb  = (bf16*)(ws + ((size_t)64 << 20));
  bf16* Vtb = (bf16*)(ws + ((size_t)96 << 20));   // [8][1024][2048]
  bf16* Rbb = (bf16*)(ws + ((size_t)128 << 20));
  bf16* WcT = (bf16*)(ws + ((size_t)160 << 20));  // [3072][1024]
  bf16* WoT = (bf16*)(ws + ((size_t)166 << 20));  // [1024][1024]

  const int M = ABATCH * ASEQ;  // 16384

  k_cast_x<<<2048, 256, 0, stream>>>(x, Xb, (M * ADIM) / 4);
  k_prep_w<<<2048, 256, 0, stream>>>(Wq, Wk, Wv, Wo, WcT, WoT);
  k_gemm8p<0><<<1536, 512, 0, stream>>>(
      Xb, WcT, bq, bk, bv, Qb, Kb, Vtb, nullptr, 24);
  k_attn<<<dim3(32, 8), 256, 0, stream>>>(Qb, Kb, Vtb, Rbb, dp);
  k_gemm8p<1><<<512, 512, 0, stream>>>(
      Rbb, WoT, bo, nullptr, nullptr, nullptr, nullptr, nullptr, out, 8);
}

// Round 4
// 242.443 us; speedup vs baseline: 1.3725x; 1.1377x over previous
//
#include <hip/hip_runtime.h>
#include <cstdint>
#include <cstddef>

typedef __bf16 bf16;
typedef __attribute__((ext_vector_type(8))) __bf16 bf16x8;
typedef __attribute__((ext_vector_type(4))) __bf16 bf16x4;
typedef __attribute__((ext_vector_type(4))) float f32x4;

#define ADIM 1024
#define ASEQ 2048
#define ABATCH 8

__device__ __forceinline__ void gload_lds16(const void* g, void* l) {
  __builtin_amdgcn_global_load_lds(
      (const __attribute__((address_space(1))) void*)g,
      (__attribute__((address_space(3))) void*)l,
      16, 0, 0);
}

__device__ __forceinline__ f32x4 mfma16(bf16x8 a, bf16x8 b, f32x4 c) {
  return __builtin_amdgcn_mfma_f32_16x16x32_bf16(a, b, c, 0, 0, 0);
}

// ---------------- cast x (fp32 -> bf16), vectorized ----------------
__global__ void k_cast_x(const float* __restrict__ x, bf16* __restrict__ xb, int n4) {
  int i = blockIdx.x * blockDim.x + threadIdx.x;
  int stride = gridDim.x * blockDim.x;
  for (; i < n4; i += stride) {
    float4 f = ((const float4*)x)[i];
    bf16x4 o = { (bf16)f.x, (bf16)f.y, (bf16)f.z, (bf16)f.w };
    ((bf16x4*)xb)[i] = o;
  }
}

// ------- weights: LDS-tiled transpose + cast (coalesced both sides) -------
// WcT[(which*1024 + n)*1024 + k] = W_which[k][n]; WoT[n][k] = Wo[k][n].
// One block per 64x64 tile; 1024 blocks total.
__global__ __launch_bounds__(256) void k_prep_w_t(
    const float* __restrict__ Wq, const float* __restrict__ Wk,
    const float* __restrict__ Wv, const float* __restrict__ Wo,
    bf16* __restrict__ WcT, bf16* __restrict__ WoT) {
  const int b = blockIdx.x;
  const int which = b >> 8, t = b & 255;
  const int n0 = (t & 15) * 64, k0 = (t >> 4) * 64;
  const float* W = (which == 0) ? Wq : (which == 1) ? Wk : (which == 2) ? Wv : Wo;
  bf16* out = (which < 3) ? (WcT + (size_t)which * ADIM * ADIM) : WoT;

  __shared__ float tile[64][69];
  const int r = threadIdx.x >> 4, c4 = (threadIdx.x & 15) * 4;
#pragma unroll
  for (int p = 0; p < 4; ++p) {
    float4 f = *(const float4*)&W[(size_t)(k0 + p * 16 + r) * ADIM + n0 + c4];
    tile[p * 16 + r][c4 + 0] = f.x;
    tile[p * 16 + r][c4 + 1] = f.y;
    tile[p * 16 + r][c4 + 2] = f.z;
    tile[p * 16 + r][c4 + 3] = f.w;
  }
  __syncthreads();
#pragma unroll
  for (int p = 0; p < 4; ++p) {
    const int nn = p * 16 + r;
    bf16x4 o;
#pragma unroll
    for (int j = 0; j < 4; ++j) o[j] = (bf16)tile[c4 + j][nn];
    *(bf16x4*)&out[(size_t)(n0 + nn) * ADIM + k0 + c4] = o;
  }
}

// ====== 256x128-tile BK=64 GEMM, 3-slot LDS tile ring, 2 phases/K-step ======
// C[m][n] = sum_k A[m][k] * BT[n][k];  512 threads = 8 waves (4 M x 2 N).
// Per K-step t: consume slot t%3, prefetch tile t+2 into slot (t+2)%3.
// Per-wave vmcnt ledger: 6 gloads/step; vmcnt(6) at step end => tile t+1
// resident entering step t+1 (never drains to 0 mid-loop).
// LDS swizzle (full 8-way spread): slot (r,c) holds global (r, c^(r&7));
// stage applies the inverse on the per-lane GLOBAL source (linear dest),
// reads use c16 = g ^ (r&7). 16-lane group -> 8 cols x 32 banks, 2-way = free.
// MODE 0: fused QKV epilogue (block's n-range lies in one of Q/K/V since
// 128 | 1024); MODE 1: fp32 out + bias.
template<int MODE>
__global__ __launch_bounds__(512, 2) void k_gemm8p(
    const bf16* __restrict__ A, const bf16* __restrict__ BT,
    const float* __restrict__ bias0, const float* __restrict__ bias1,
    const float* __restrict__ bias2,
    bf16* __restrict__ Qo, bf16* __restrict__ Ko, bf16* __restrict__ Vto,
    float* __restrict__ outF, int ntn)
{
  constexpr int K = 1024;
  constexpr int KT = K / 64;   // 16
  const int nwg = gridDim.x;
  const int cpx = nwg >> 3;
  const int flat = blockIdx.x;
  const int sw = (flat & 7) * cpx + (flat >> 3);   // grid % 8 == 0 (bijective)
  const int bx = sw % ntn, by = sw / ntn;
  const int m0 = by * 256, n0 = bx * 128;

  const int tid = threadIdx.x;
  const int l = tid & 63, w = tid >> 6;
  const int wm = w >> 1, wn = w & 1;
  const int lr = l & 15, kg = l >> 4;

  __shared__ alignas(16) bf16 sA[3][256 * 64];   // 96 KiB
  __shared__ alignas(16) bf16 sB[3][128 * 64];   // 48 KiB

  f32x4 acc[4][4] = {};

  // precomputed swizzled ds_read byte offsets
  int oA[4][2], oB[2][2][2];
#pragma unroll
  for (int i = 0; i < 4; ++i)
#pragma unroll
    for (int ks = 0; ks < 2; ++ks) {
      int r = wm * 64 + i * 16 + lr;
      int c16 = (ks * 4 + kg) ^ (r & 7);
      oA[i][ks] = (r * 8 + c16) * 16;
    }
#pragma unroll
  for (int h = 0; h < 2; ++h)
#pragma unroll
    for (int j = 0; j < 2; ++j)
#pragma unroll
      for (int ks = 0; ks < 2; ++ks) {
        int r = wn * 64 + h * 32 + j * 16 + lr;
        int c16 = (ks * 4 + kg) ^ (r & 7);
        oB[h][j][ks] = (r * 8 + c16) * 16;
      }

  auto stageA = [&](int sp, int kt2, int c) {
    int u = c * 512 + tid;
    int prow = u >> 3, pc = u & 7;
    int lc = pc ^ (prow & 7);                     // inverse swizzle on source
    gload_lds16(A + (size_t)(m0 + prow) * K + kt2 * 64 + lc * 8,
                &sA[sp][(c * 512 + w * 64) * 8]);
  };
  auto stageB = [&](int sp, int kt2, int c) {
    int u = c * 512 + tid;
    int prow = u >> 3, pc = u & 7;
    int lc = pc ^ (prow & 7);
    gload_lds16(BT + (size_t)(n0 + prow) * K + kt2 * 64 + lc * 8,
                &sB[sp][(c * 512 + w * 64) * 8]);
  };

  // prologue: tiles 0 and 1 (12 gloads/thread), then require tile 0 resident
#pragma unroll
  for (int tt = 0; tt < 2; ++tt) {
    stageA(tt, tt, 0); stageA(tt, tt, 1); stageA(tt, tt, 2); stageA(tt, tt, 3);
    stageB(tt, tt, 0); stageB(tt, tt, 1);
  }
  asm volatile("s_waitcnt vmcnt(6)" ::: "memory");
  __builtin_amdgcn_s_barrier();
  asm volatile("" ::: "memory");

  for (int t = 0; t < KT; ++t) {
    const int s = t % 3, sp = (t + 2) % 3;
    const int tpc = (t + 2 < KT) ? t + 2 : t;    // dummy re-stage: uniform ledger
    const char* bA = (const char*)&sA[s][0];
    const char* bB = (const char*)&sB[s][0];

    // ---------------- phase 0: cols 0..31 ----------------
    bf16x8 af[4][2], b0[2][2];
#pragma unroll
    for (int i = 0; i < 4; ++i)
#pragma unroll
      for (int ks = 0; ks < 2; ++ks)
        af[i][ks] = *(const bf16x8*)(bA + oA[i][ks]);
#pragma unroll
    for (int j = 0; j < 2; ++j)
#pragma unroll
      for (int ks = 0; ks < 2; ++ks)
        b0[j][ks] = *(const bf16x8*)(bB + oB[0][j][ks]);
    stageA(sp, tpc, 0); stageA(sp, tpc, 1); stageB(sp, tpc, 0);
    asm volatile("" ::: "memory");
    __builtin_amdgcn_s_barrier();
    asm volatile("" ::: "memory");
    __builtin_amdgcn_s_setprio(1);
#pragma unroll
    for (int i = 0; i < 4; ++i)
#pragma unroll
      for (int j = 0; j < 2; ++j)
#pragma unroll
        for (int ks = 0; ks < 2; ++ks)
          acc[i][j] = mfma16(af[i][ks], b0[j][ks], acc[i][j]);
    __builtin_amdgcn_s_setprio(0);
    asm volatile("" ::: "memory");
    __builtin_amdgcn_s_barrier();
    asm volatile("" ::: "memory");

    // ---------------- phase 1: cols 32..63 ----------------
    bf16x8 b1[2][2];
#pragma unroll
    for (int j = 0; j < 2; ++j)
#pragma unroll
      for (int ks = 0; ks < 2; ++ks)
        b1[j][ks] = *(const bf16x8*)(bB + oB[1][j][ks]);
    stageA(sp, tpc, 2); stageA(sp, tpc, 3); stageB(sp, tpc, 1);
    asm volatile("" ::: "memory");
    __builtin_amdgcn_s_barrier();
    asm volatile("" ::: "memory");
    __builtin_amdgcn_s_setprio(1);
#pragma unroll
    for (int i = 0; i < 4; ++i)
#pragma unroll
      for (int j = 0; j < 2; ++j)
#pragma unroll
        for (int ks = 0; ks < 2; ++ks)
          acc[i][2 + j] = mfma16(af[i][ks], b1[j][ks], acc[i][2 + j]);
    __builtin_amdgcn_s_setprio(0);
    asm volatile("s_waitcnt vmcnt(6)" ::: "memory");   // tile t+1 now resident
    __builtin_amdgcn_s_barrier();
    asm volatile("" ::: "memory");
  }
  asm volatile("s_waitcnt vmcnt(0)" ::: "memory");     // drain tail dummies

  // ---- epilogue ----
  const int cb = n0 >> 10;          // uniform per block (128 | 1024)
#pragma unroll
  for (int i = 0; i < 4; ++i) {
#pragma unroll
    for (int jj = 0; jj < 4; ++jj) {
      const int n = n0 + wn * 64 + jj * 16 + lr;
      const int m0r = m0 + wm * 64 + i * 16 + kg * 4;
      if (MODE == 0) {
        const int nn = n & 1023;
        if (cb == 0) {
          const float b_ = bias0[nn];
#pragma unroll
          for (int r = 0; r < 4; ++r)
            Qo[(size_t)(m0r + r) * ADIM + nn] = (bf16)(acc[i][jj][r] + b_);
        } else if (cb == 1) {
          const float b_ = bias1[nn];
#pragma unroll
          for (int r = 0; r < 4; ++r) {
            float v = acc[i][jj][r] + b_;
            Ko[(size_t)(m0r + r) * ADIM + nn] = (bf16)(v > 0.f ? v + 1.f : __expf(v));
          }
        } else {
          const float b_ = bias2[nn];
          const int bb = m0r >> 11, t0c = m0r & 2047;
          bf16x4 pk;
#pragma unroll
          for (int r = 0; r < 4; ++r) pk[r] = (bf16)(acc[i][jj][r] + b_);
          *(bf16x4*)&Vto[((size_t)bb * ADIM + nn) * ASEQ + t0c] = pk;
        }
      } else {
        const float b_ = bias0[n];
#pragma unroll
        for (int r = 0; r < 4; ++r)
          outF[(size_t)(m0r + r) * ADIM + n] = acc[i][jj][r] + b_;
      }
    }
  }
}

// --------- windowed decay attention: one (batch, 64-row q-tile) per WG ---------
__global__ __launch_bounds__(256) void k_attn(
    const bf16* __restrict__ Qg, const bf16* __restrict__ Kg,
    const bf16* __restrict__ Vt, bf16* __restrict__ Rb,
    const float* __restrict__ decay_param)
{
  const int b = blockIdx.y;
  const int T0 = blockIdx.x * 64;
  const int tid = threadIdx.x;
  const int l = tid & 63, w = tid >> 6;
  const int lr = l & 15, lk = (l >> 4) * 8;

  const float dp = decay_param[0];
  const float decay = 1.f / (1.f + __expf(-dp));
  const float l2d = __log2f(decay);

  __shared__ alignas(16) bf16 lQ[2][64 * 32];
  __shared__ alignas(16) bf16 lK[2][128 * 32];
  __shared__ alignas(16) bf16 lV[2][128 * 32];
  __shared__ alignas(16) bf16 lP[64 * 136];

  const bf16* Qb = Qg + (size_t)(b * ASEQ + T0) * ADIM;

  auto stageQK = [&](int buf, int k0) {
    {
      const bf16* g = Qb + (size_t)(w * 16 + (l >> 2)) * ADIM + k0 + (l & 3) * 8;
      gload_lds16(g, &lQ[buf][w * 16 * 32]);
    }
#pragma unroll
    for (int cc = 0; cc < 2; ++cc) {
      int c = 2 * w + cc;
      int sg = T0 - 64 + c * 16 + (l >> 2);
      if (sg < 0) sg = 0;
      const bf16* g = Kg + (size_t)(b * ASEQ + sg) * ADIM + k0 + (l & 3) * 8;
      gload_lds16(g, &lK[buf][c * 16 * 32]);
    }
  };

  f32x4 sc[4][2] = {};
  stageQK(0, 0);
  __syncthreads();
  for (int kt = 0; kt < 32; ++kt) {
    int cur = kt & 1;
    if (kt + 1 < 32) stageQK(cur ^ 1, (kt + 1) * 32);
    bf16x8 af[4], bfr[2];
#pragma unroll
    for (int i = 0; i < 4; ++i)
      af[i] = *(const bf16x8*)&lQ[cur][(i * 16 + lr) * 32 + lk];
#pragma unroll
    for (int j = 0; j < 2; ++j)
      bfr[j] = *(const bf16x8*)&lK[cur][(w * 32 + j * 16 + lr) * 32 + lk];
#pragma unroll
    for (int i = 0; i < 4; ++i)
#pragma unroll
      for (int j = 0; j < 2; ++j)
        sc[i][j] = mfma16(af[i], bfr[j], sc[i][j]);
    __syncthreads();
  }

  const int er = (l >> 4) * 4, ec = l & 15;
#pragma unroll
  for (int i = 0; i < 4; ++i)
#pragma unroll
    for (int j = 0; j < 2; ++j)
#pragma unroll
      for (int r = 0; r < 4; ++r) {
        int tl = i * 16 + er + r;
        int sl = w * 32 + j * 16 + ec;
        int sg = T0 - 64 + sl;
        int delta = (T0 + tl) - 1 - sg;
        float wgt = (delta >= 0 && delta < 64 && sg >= 0)
                        ? exp2f((float)delta * l2d) : 0.f;
        lP[tl * 136 + sl] = (bf16)(sc[i][j][r] * wgt);
      }

  auto stageV = [&](int buf, int g) {
    int nc = g >> 2, ks = g & 3;
#pragma unroll
    for (int cc = 0; cc < 2; ++cc) {
      int c = 2 * w + cc;
      int drow = nc * 128 + c * 16 + (l >> 2);
      int scol = T0 - 64 + ks * 32 + (l & 3) * 8;
      if (scol < 0) scol = 0;
      const bf16* gv = Vt + ((size_t)b * ADIM + drow) * ASEQ + scol;
      gload_lds16(gv, &lV[buf][c * 16 * 32]);
    }
  };

  f32x4 o[4][2] = {};
  stageV(0, 0);
  __syncthreads();

  for (int g = 0; g < 32; ++g) {
    int cur = g & 1;
    if (g + 1 < 32) stageV(cur ^ 1, g + 1);
    int nc = g >> 2, ks = g & 3;
    bf16x8 af[4], bfr[2];
#pragma unroll
    for (int i = 0; i < 4; ++i)
      af[i] = *(const bf16x8*)&lP[(i * 16 + lr) * 136 + ks * 32 + lk];
#pragma unroll
    for (int j = 0; j < 2; ++j)
      bfr[j] = *(const bf16x8*)&lV[cur][(w * 32 + j * 16 + lr) * 32 + lk];
#pragma unroll
    for (int i = 0; i < 4; ++i)
#pragma unroll
      for (int j = 0; j < 2; ++j)
        o[i][j] = mfma16(af[i], bfr[j], o[i][j]);
    if (ks == 3) {
#pragma unroll
      for (int i = 0; i < 4; ++i)
#pragma unroll
        for (int j = 0; j < 2; ++j) {
#pragma unroll
          for (int r = 0; r < 4; ++r) {
            int tl = i * 16 + er + r;
            int dl = nc * 128 + w * 32 + j * 16 + ec;
            Rb[(size_t)(b * ASEQ + T0 + tl) * ADIM + dl] = (bf16)o[i][j][r];
          }
#pragma unroll
          for (int r = 0; r < 4; ++r) o[i][j][r] = 0.f;
        }
    }
    __syncthreads();
  }
}

extern "C" void kernel_launch(void* const* d_in, const int* in_sizes, int n_in,
                              void* d_out, int out_size, void* d_ws, size_t ws_size,
                              hipStream_t stream) {
  const float* x  = (const float*)d_in[0];
  const float* Wq = (const float*)d_in[1];
  const float* bq = (const float*)d_in[2];
  const float* Wk = (const float*)d_in[3];
  const float* bk = (const float*)d_in[4];
  const float* Wv = (const float*)d_in[5];
  const float* bv = (const float*)d_in[6];
  const float* Wo = (const float*)d_in[7];
  const float* bo = (const float*)d_in[8];
  const float* dp = (const float*)d_in[9];
  float* out = (float*)d_out;

  char* ws = (char*)d_ws;
  bf16* Xb  = (bf16*)(ws + ((size_t)0 << 20));    // [16384][1024]
  bf16* Qb  = (bf16*)(ws + ((size_t)32 << 20));
  bf16* Kb  = (bf16*)(ws + ((size_t)64 << 20));
  bf16* Vtb = (bf16*)(ws + ((size_t)96 << 20));   // [8][1024][2048]
  bf16* Rbb = (bf16*)(ws + ((size_t)128 << 20));
  bf16* WcT = (bf16*)(ws + ((size_t)160 << 20));  // [3072][1024]
  bf16* WoT = (bf16*)(ws + ((size_t)166 << 20));  // [1024][1024]

  const int M = ABATCH * ASEQ;  // 16384

  k_cast_x<<<2048, 256, 0, stream>>>(x, Xb, (M * ADIM) / 4);
  k_prep_w_t<<<1024, 256, 0, stream>>>(Wq, Wk, Wv, Wo, WcT, WoT);
  k_gemm8p<0><<<1536, 512, 0, stream>>>(
      Xb, WcT, bq, bk, bv, Qb, Kb, Vtb, nullptr, 24);
  k_attn<<<dim3(32, 8), 256, 0, stream>>>(Qb, Kb, Vtb, Rbb, dp);
  k_gemm8p<1><<<512, 512, 0, stream>>>(
      Rbb, WoT, bo, nullptr, nullptr, nullptr, nullptr, nullptr, out, 8);
}

// Round 5
// 232.502 us; speedup vs baseline: 1.4312x; 1.0428x over previous
//
#include <hip/hip_runtime.h>
#include <cstdint>
#include <cstddef>

typedef __bf16 bf16;
typedef __attribute__((ext_vector_type(8))) __bf16 bf16x8;
typedef __attribute__((ext_vector_type(4))) __bf16 bf16x4;
typedef __attribute__((ext_vector_type(4))) float f32x4;

#define ADIM 1024
#define ASEQ 2048
#define ABATCH 8

__device__ __forceinline__ void gload_lds16(const void* g, void* l) {
  __builtin_amdgcn_global_load_lds(
      (const __attribute__((address_space(1))) void*)g,
      (__attribute__((address_space(3))) void*)l,
      16, 0, 0);
}

__device__ __forceinline__ f32x4 mfma16(bf16x8 a, bf16x8 b, f32x4 c) {
  return __builtin_amdgcn_mfma_f32_16x16x32_bf16(a, b, c, 0, 0, 0);
}

// ---------------- cast x (fp32 -> bf16), vectorized ----------------
__global__ void k_cast_x(const float* __restrict__ x, bf16* __restrict__ xb, int n4) {
  int i = blockIdx.x * blockDim.x + threadIdx.x;
  int stride = gridDim.x * blockDim.x;
  for (; i < n4; i += stride) {
    float4 f = ((const float4*)x)[i];
    bf16x4 o = { (bf16)f.x, (bf16)f.y, (bf16)f.z, (bf16)f.w };
    ((bf16x4*)xb)[i] = o;
  }
}

// ------- weights: LDS-tiled transpose + cast (coalesced both sides) -------
__global__ __launch_bounds__(256) void k_prep_w_t(
    const float* __restrict__ Wq, const float* __restrict__ Wk,
    const float* __restrict__ Wv, const float* __restrict__ Wo,
    bf16* __restrict__ WcT, bf16* __restrict__ WoT) {
  const int b = blockIdx.x;
  const int which = b >> 8, t = b & 255;
  const int n0 = (t & 15) * 64, k0 = (t >> 4) * 64;
  const float* W = (which == 0) ? Wq : (which == 1) ? Wk : (which == 2) ? Wv : Wo;
  bf16* out = (which < 3) ? (WcT + (size_t)which * ADIM * ADIM) : WoT;

  __shared__ float tile[64][69];
  const int r = threadIdx.x >> 4, c4 = (threadIdx.x & 15) * 4;
#pragma unroll
  for (int p = 0; p < 4; ++p) {
    float4 f = *(const float4*)&W[(size_t)(k0 + p * 16 + r) * ADIM + n0 + c4];
    tile[p * 16 + r][c4 + 0] = f.x;
    tile[p * 16 + r][c4 + 1] = f.y;
    tile[p * 16 + r][c4 + 2] = f.z;
    tile[p * 16 + r][c4 + 3] = f.w;
  }
  __syncthreads();
#pragma unroll
  for (int p = 0; p < 4; ++p) {
    const int nn = p * 16 + r;
    bf16x4 o;
#pragma unroll
    for (int j = 0; j < 4; ++j) o[j] = (bf16)tile[c4 + j][nn];
    *(bf16x4*)&out[(size_t)(n0 + nn) * ADIM + k0 + c4] = o;
  }
}

// ====== 256x256-tile BK=32 GEMM, 3-slot ring, m201 wave geometry ======
// C[m][n] = sum_k A[m][k]*BT[n][k]; 512 threads = 8 waves (2M x 4N),
// per-wave output 128x64 (acc[8][4]) -> 0.375 ds_reads/MFMA.
// Ring: compute slot t%3, stage tile t+2 into (t+2)%3; 4 gloads/thread/step;
// vmcnt(4) at step end (tile t+1 resident, t+2's 4 still in flight).
// LDS row = 32 bf16 = 4 x 16B slots; slot (r,s) holds global (r, s^((r>>1)&3))
// (involution; inverse applied on per-lane GLOBAL source, linear gload dest;
// readers: 8 even rows over 4 slots = 2/bank = conflict-free).
// 2 phases/K-step: {8 or 4 ds_read_b128 || 2 gloads, barrier, 16 MFMA, barrier}.
// MODE 0: fused QKV epilogue (256 | 1024 so block n-range uniform);
// MODE 1: fp32 out + bias.
template<int MODE>
__global__ __launch_bounds__(512, 2) void k_gemm2x(
    const bf16* __restrict__ A, const bf16* __restrict__ BT,
    const float* __restrict__ bias0, const float* __restrict__ bias1,
    const float* __restrict__ bias2,
    bf16* __restrict__ Qo, bf16* __restrict__ Ko, bf16* __restrict__ Vto,
    float* __restrict__ outF, int ntn)
{
  constexpr int K = 1024;
  constexpr int KT = K / 32;   // 32 steps of BK=32
  const int nwg = gridDim.x;
  const int cpx = nwg >> 3;
  const int flat = blockIdx.x;
  const int sw = (flat & 7) * cpx + (flat >> 3);   // grid % 8 == 0 (bijective)
  const int bx = sw % ntn, by = sw / ntn;
  const int m0 = by * 256, n0 = bx * 256;

  const int tid = threadIdx.x;
  const int l = tid & 63, w = tid >> 6;
  const int wm = w >> 2, wn = w & 3;     // 2M x 4N
  const int lr = l & 15, kg = l >> 4;    // kg in 0..3 (col16 within BK=32)

  __shared__ alignas(16) bf16 sA[3][256 * 32];   // 48 KiB
  __shared__ alignas(16) bf16 sB[3][256 * 32];   // 48 KiB

  f32x4 acc[8][4] = {};

  // swizzled ds_read byte offsets: want global col16=kg of row r
  int oA[8], oB[4];
#pragma unroll
  for (int i = 0; i < 8; ++i) {
    int r = wm * 128 + i * 16 + lr;
    oA[i] = (r * 4 + (kg ^ ((r >> 1) & 3))) * 16;
  }
#pragma unroll
  for (int j = 0; j < 4; ++j) {
    int r = wn * 64 + j * 16 + lr;
    oB[j] = (r * 4 + (kg ^ ((r >> 1) & 3))) * 16;
  }

  auto stageA = [&](int sp, int kt, int half) {
    int u = half * 512 + tid;
    int prow = u >> 2, ps = u & 3;
    int lc = ps ^ ((prow >> 1) & 3);              // inverse swizzle on source
    gload_lds16(A + (size_t)(m0 + prow) * K + kt * 32 + lc * 8,
                &sA[sp][(half * 512 + w * 64) * 8]);
  };
  auto stageB = [&](int sp, int kt, int half) {
    int u = half * 512 + tid;
    int prow = u >> 2, ps = u & 3;
    int lc = ps ^ ((prow >> 1) & 3);
    gload_lds16(BT + (size_t)(n0 + prow) * K + kt * 32 + lc * 8,
                &sB[sp][(half * 512 + w * 64) * 8]);
  };

  // prologue: tiles 0,1 (8 gloads); require tile 0 resident (4 newest fly)
#pragma unroll
  for (int tt = 0; tt < 2; ++tt) {
    stageA(tt, tt, 0); stageB(tt, tt, 0);
    stageA(tt, tt, 1); stageB(tt, tt, 1);
  }
  asm volatile("s_waitcnt vmcnt(4)" ::: "memory");
  __builtin_amdgcn_s_barrier();
  asm volatile("" ::: "memory");

  for (int t = 0; t < KT; ++t) {
    const int s = t % 3, sp = (t + 2) % 3;
    const int tpc = (t + 2 < KT) ? t + 2 : t;    // dummy tail: uniform ledger
    const char* bA = (const char*)&sA[s][0];
    const char* bB = (const char*)&sB[s][0];

    bf16x8 af[8], bfr[4];
    // ---------------- phase 0: M-rows 0..63 of wave tile ----------------
#pragma unroll
    for (int i = 0; i < 4; ++i) af[i] = *(const bf16x8*)(bA + oA[i]);
#pragma unroll
    for (int j = 0; j < 4; ++j) bfr[j] = *(const bf16x8*)(bB + oB[j]);
    stageA(sp, tpc, 0); stageB(sp, tpc, 0);
    asm volatile("" ::: "memory");
    __builtin_amdgcn_s_barrier();
    asm volatile("" ::: "memory");
    __builtin_amdgcn_s_setprio(1);
#pragma unroll
    for (int i = 0; i < 4; ++i)
#pragma unroll
      for (int j = 0; j < 4; ++j)
        acc[i][j] = mfma16(af[i], bfr[j], acc[i][j]);
    __builtin_amdgcn_s_setprio(0);
    asm volatile("" ::: "memory");
    __builtin_amdgcn_s_barrier();
    asm volatile("" ::: "memory");

    // ---------------- phase 1: M-rows 64..127 ----------------
#pragma unroll
    for (int i = 4; i < 8; ++i) af[i] = *(const bf16x8*)(bA + oA[i]);
    stageA(sp, tpc, 1); stageB(sp, tpc, 1);
    asm volatile("" ::: "memory");
    __builtin_amdgcn_s_barrier();
    asm volatile("" ::: "memory");
    __builtin_amdgcn_s_setprio(1);
#pragma unroll
    for (int i = 4; i < 8; ++i)
#pragma unroll
      for (int j = 0; j < 4; ++j)
        acc[i][j] = mfma16(af[i], bfr[j], acc[i][j]);
    __builtin_amdgcn_s_setprio(0);
    asm volatile("s_waitcnt vmcnt(4)" ::: "memory");   // tile t+1 resident
    __builtin_amdgcn_s_barrier();
    asm volatile("" ::: "memory");
  }
  asm volatile("s_waitcnt vmcnt(0)" ::: "memory");     // drain tail dummies

  // ---- epilogue ----
  const int cb = n0 >> 10;          // uniform per block (256 | 1024)
#pragma unroll
  for (int i = 0; i < 8; ++i) {
#pragma unroll
    for (int jj = 0; jj < 4; ++jj) {
      const int n = n0 + wn * 64 + jj * 16 + lr;
      const int m0r = m0 + wm * 128 + i * 16 + kg * 4;
      if (MODE == 0) {
        const int nn = n & 1023;
        if (cb == 0) {
          const float b_ = bias0[nn];
#pragma unroll
          for (int r = 0; r < 4; ++r)
            Qo[(size_t)(m0r + r) * ADIM + nn] = (bf16)(acc[i][jj][r] + b_);
        } else if (cb == 1) {
          const float b_ = bias1[nn];
#pragma unroll
          for (int r = 0; r < 4; ++r) {
            float v = acc[i][jj][r] + b_;
            Ko[(size_t)(m0r + r) * ADIM + nn] = (bf16)(v > 0.f ? v + 1.f : __expf(v));
          }
        } else {
          const float b_ = bias2[nn];
          const int bb = m0r >> 11, t0c = m0r & 2047;
          bf16x4 pk;
#pragma unroll
          for (int r = 0; r < 4; ++r) pk[r] = (bf16)(acc[i][jj][r] + b_);
          *(bf16x4*)&Vto[((size_t)bb * ADIM + nn) * ASEQ + t0c] = pk;
        }
      } else {
        const float b_ = bias0[n];
#pragma unroll
        for (int r = 0; r < 4; ++r)
          outF[(size_t)(m0r + r) * ADIM + n] = acc[i][jj][r] + b_;
      }
    }
  }
}

// --------- windowed decay attention: one (batch, 64-row q-tile) per WG ---------
__global__ __launch_bounds__(256) void k_attn(
    const bf16* __restrict__ Qg, const bf16* __restrict__ Kg,
    const bf16* __restrict__ Vt, bf16* __restrict__ Rb,
    const float* __restrict__ decay_param)
{
  const int b = blockIdx.y;
  const int T0 = blockIdx.x * 64;
  const int tid = threadIdx.x;
  const int l = tid & 63, w = tid >> 6;
  const int lr = l & 15, lk = (l >> 4) * 8;

  const float dp = decay_param[0];
  const float decay = 1.f / (1.f + __expf(-dp));
  const float l2d = __log2f(decay);

  __shared__ alignas(16) bf16 lQ[2][64 * 32];
  __shared__ alignas(16) bf16 lK[2][128 * 32];
  __shared__ alignas(16) bf16 lV[2][128 * 32];
  __shared__ alignas(16) bf16 lP[64 * 136];

  const bf16* Qb = Qg + (size_t)(b * ASEQ + T0) * ADIM;

  auto stageQK = [&](int buf, int k0) {
    {
      const bf16* g = Qb + (size_t)(w * 16 + (l >> 2)) * ADIM + k0 + (l & 3) * 8;
      gload_lds16(g, &lQ[buf][w * 16 * 32]);
    }
#pragma unroll
    for (int cc = 0; cc < 2; ++cc) {
      int c = 2 * w + cc;
      int sg = T0 - 64 + c * 16 + (l >> 2);
      if (sg < 0) sg = 0;
      const bf16* g = Kg + (size_t)(b * ASEQ + sg) * ADIM + k0 + (l & 3) * 8;
      gload_lds16(g, &lK[buf][c * 16 * 32]);
    }
  };

  f32x4 sc[4][2] = {};
  stageQK(0, 0);
  __syncthreads();
  for (int kt = 0; kt < 32; ++kt) {
    int cur = kt & 1;
    if (kt + 1 < 32) stageQK(cur ^ 1, (kt + 1) * 32);
    bf16x8 af[4], bfr[2];
#pragma unroll
    for (int i = 0; i < 4; ++i)
      af[i] = *(const bf16x8*)&lQ[cur][(i * 16 + lr) * 32 + lk];
#pragma unroll
    for (int j = 0; j < 2; ++j)
      bfr[j] = *(const bf16x8*)&lK[cur][(w * 32 + j * 16 + lr) * 32 + lk];
#pragma unroll
    for (int i = 0; i < 4; ++i)
#pragma unroll
      for (int j = 0; j < 2; ++j)
        sc[i][j] = mfma16(af[i], bfr[j], sc[i][j]);
    __syncthreads();
  }

  const int er = (l >> 4) * 4, ec = l & 15;
#pragma unroll
  for (int i = 0; i < 4; ++i)
#pragma unroll
    for (int j = 0; j < 2; ++j)
#pragma unroll
      for (int r = 0; r < 4; ++r) {
        int tl = i * 16 + er + r;
        int sl = w * 32 + j * 16 + ec;
        int sg = T0 - 64 + sl;
        int delta = (T0 + tl) - 1 - sg;
        float wgt = (delta >= 0 && delta < 64 && sg >= 0)
                        ? exp2f((float)delta * l2d) : 0.f;
        lP[tl * 136 + sl] = (bf16)(sc[i][j][r] * wgt);
      }

  auto stageV = [&](int buf, int g) {
    int nc = g >> 2, ks = g & 3;
#pragma unroll
    for (int cc = 0; cc < 2; ++cc) {
      int c = 2 * w + cc;
      int drow = nc * 128 + c * 16 + (l >> 2);
      int scol = T0 - 64 + ks * 32 + (l & 3) * 8;
      if (scol < 0) scol = 0;
      const bf16* gv = Vt + ((size_t)b * ADIM + drow) * ASEQ + scol;
      gload_lds16(gv, &lV[buf][c * 16 * 32]);
    }
  };

  f32x4 o[4][2] = {};
  stageV(0, 0);
  __syncthreads();

  for (int g = 0; g < 32; ++g) {
    int cur = g & 1;
    if (g + 1 < 32) stageV(cur ^ 1, g + 1);
    int nc = g >> 2, ks = g & 3;
    bf16x8 af[4], bfr[2];
#pragma unroll
    for (int i = 0; i < 4; ++i)
      af[i] = *(const bf16x8*)&lP[(i * 16 + lr) * 136 + ks * 32 + lk];
#pragma unroll
    for (int j = 0; j < 2; ++j)
      bfr[j] = *(const bf16x8*)&lV[cur][(w * 32 + j * 16 + lr) * 32 + lk];
#pragma unroll
    for (int i = 0; i < 4; ++i)
#pragma unroll
      for (int j = 0; j < 2; ++j)
        o[i][j] = mfma16(af[i], bfr[j], o[i][j]);
    if (ks == 3) {
#pragma unroll
      for (int i = 0; i < 4; ++i)
#pragma unroll
        for (int j = 0; j < 2; ++j) {
#pragma unroll
          for (int r = 0; r < 4; ++r) {
            int tl = i * 16 + er + r;
            int dl = nc * 128 + w * 32 + j * 16 + ec;
            Rb[(size_t)(b * ASEQ + T0 + tl) * ADIM + dl] = (bf16)o[i][j][r];
          }
#pragma unroll
          for (int r = 0; r < 4; ++r) o[i][j][r] = 0.f;
        }
    }
    __syncthreads();
  }
}

extern "C" void kernel_launch(void* const* d_in, const int* in_sizes, int n_in,
                              void* d_out, int out_size, void* d_ws, size_t ws_size,
                              hipStream_t stream) {
  const float* x  = (const float*)d_in[0];
  const float* Wq = (const float*)d_in[1];
  const float* bq = (const float*)d_in[2];
  const float* Wk = (const float*)d_in[3];
  const float* bk = (const float*)d_in[4];
  const float* Wv = (const float*)d_in[5];
  const float* bv = (const float*)d_in[6];
  const float* Wo = (const float*)d_in[7];
  const float* bo = (const float*)d_in[8];
  const float* dp = (const float*)d_in[9];
  float* out = (float*)d_out;

  char* ws = (char*)d_ws;
  bf16* Xb  = (bf16*)(ws + ((size_t)0 << 20));    // [16384][1024]
  bf16* Qb  = (bf16*)(ws + ((size_t)32 << 20));
  bf16* Kb  = (bf16*)(ws + ((size_t)64 << 20));
  bf16* Vtb = (bf16*)(ws + ((size_t)96 << 20));   // [8][1024][2048]
  bf16* Rbb = (bf16*)(ws + ((size_t)128 << 20));
  bf16* WcT = (bf16*)(ws + ((size_t)160 << 20));  // [3072][1024]
  bf16* WoT = (bf16*)(ws + ((size_t)166 << 20));  // [1024][1024]

  const int M = ABATCH * ASEQ;  // 16384

  k_cast_x<<<2048, 256, 0, stream>>>(x, Xb, (M * ADIM) / 4);
  k_prep_w_t<<<1024, 256, 0, stream>>>(Wq, Wk, Wv, Wo, WcT, WoT);
  k_gemm2x<0><<<768, 512, 0, stream>>>(
      Xb, WcT, bq, bk, bv, Qb, Kb, Vtb, nullptr, 12);
  k_attn<<<dim3(32, 8), 256, 0, stream>>>(Qb, Kb, Vtb, Rbb, dp);
  k_gemm2x<1><<<256, 512, 0, stream>>>(
      Rbb, WoT, bo, nullptr, nullptr, nullptr, nullptr, nullptr, out, 4);
}

// Round 6
// 219.845 us; speedup vs baseline: 1.5136x; 1.0576x over previous
//
#include <hip/hip_runtime.h>
#include <cstdint>
#include <cstddef>

typedef __bf16 bf16;
typedef __attribute__((ext_vector_type(8))) __bf16 bf16x8;
typedef __attribute__((ext_vector_type(4))) __bf16 bf16x4;
typedef __attribute__((ext_vector_type(4))) float f32x4;

#define ADIM 1024
#define ASEQ 2048
#define ABATCH 8

__device__ __forceinline__ void gload_lds16(const void* g, void* l) {
  __builtin_amdgcn_global_load_lds(
      (const __attribute__((address_space(1))) void*)g,
      (__attribute__((address_space(3))) void*)l,
      16, 0, 0);
}

__device__ __forceinline__ f32x4 mfma16(bf16x8 a, bf16x8 b, f32x4 c) {
  return __builtin_amdgcn_mfma_f32_16x16x32_bf16(a, b, c, 0, 0, 0);
}

// ---------------- cast x (fp32 -> bf16), vectorized ----------------
__global__ void k_cast_x(const float* __restrict__ x, bf16* __restrict__ xb, int n4) {
  int i = blockIdx.x * blockDim.x + threadIdx.x;
  int stride = gridDim.x * blockDim.x;
  for (; i < n4; i += stride) {
    float4 f = ((const float4*)x)[i];
    bf16x4 o = { (bf16)f.x, (bf16)f.y, (bf16)f.z, (bf16)f.w };
    ((bf16x4*)xb)[i] = o;
  }
}

// ------- weights: LDS-tiled transpose + cast (coalesced both sides) -------
__global__ __launch_bounds__(256) void k_prep_w_t(
    const float* __restrict__ Wq, const float* __restrict__ Wk,
    const float* __restrict__ Wv, const float* __restrict__ Wo,
    bf16* __restrict__ WcT, bf16* __restrict__ WoT) {
  const int b = blockIdx.x;
  const int which = b >> 8, t = b & 255;
  const int n0 = (t & 15) * 64, k0 = (t >> 4) * 64;
  const float* W = (which == 0) ? Wq : (which == 1) ? Wk : (which == 2) ? Wv : Wo;
  bf16* out = (which < 3) ? (WcT + (size_t)which * ADIM * ADIM) : WoT;

  __shared__ float tile[64][69];
  const int r = threadIdx.x >> 4, c4 = (threadIdx.x & 15) * 4;
#pragma unroll
  for (int p = 0; p < 4; ++p) {
    float4 f = *(const float4*)&W[(size_t)(k0 + p * 16 + r) * ADIM + n0 + c4];
    tile[p * 16 + r][c4 + 0] = f.x;
    tile[p * 16 + r][c4 + 1] = f.y;
    tile[p * 16 + r][c4 + 2] = f.z;
    tile[p * 16 + r][c4 + 3] = f.w;
  }
  __syncthreads();
#pragma unroll
  for (int p = 0; p < 4; ++p) {
    const int nn = p * 16 + r;
    bf16x4 o;
#pragma unroll
    for (int j = 0; j < 4; ++j) o[j] = (bf16)tile[c4 + j][nn];
    *(bf16x4*)&out[(size_t)(n0 + nn) * ADIM + k0 + c4] = o;
  }
}

// ====== 256x256-tile BK=32 GEMM, 3-slot ring, ONE barrier per K-step ======
// C[m][n] = sum_k A[m][k]*BT[n][k]; 512 threads = 8 waves (2M x 4N),
// per-wave output 128x64 (acc[8][4]).
// Ring: read slot t%3, stage tile t+2 into slot (t+2)%3 (4 gloads/thread).
// Single fence per step: s_waitcnt vmcnt(4) + s_barrier. Race-freedom:
//  - residency: vmcnt(4) retires the oldest 4 loads = tile t+1 (in-order
//    retirement, m135); barrier makes it block-wide.
//  - WAR: slot (t+2)%3 == slot (t-1)%3 was last read at step t-1; those
//    ds_reads complete before their MFMAs (lgkm dep), which precede the
//    step-(t-1) barrier; the overwriting gloads are issued after it.
// No intra-step barriers: compiler interleaves ds_read/gload/MFMA freely,
// waves drift -> LDS and MFMA pipes overlap.
// LDS row = 32 bf16 = 4 x 16B slots; slot (r,s) holds global (r, s^((r>>1)&3))
// (involution; inverse applied on per-lane GLOBAL source, linear gload dest).
// MODE 0: fused QKV epilogue (256 | 1024 so block n-range uniform);
// MODE 1: fp32 out + bias.
template<int MODE>
__global__ __launch_bounds__(512, 2) void k_gemm2x(
    const bf16* __restrict__ A, const bf16* __restrict__ BT,
    const float* __restrict__ bias0, const float* __restrict__ bias1,
    const float* __restrict__ bias2,
    bf16* __restrict__ Qo, bf16* __restrict__ Ko, bf16* __restrict__ Vto,
    float* __restrict__ outF, int ntn)
{
  constexpr int K = 1024;
  constexpr int KT = K / 32;   // 32 steps of BK=32
  const int nwg = gridDim.x;
  const int cpx = nwg >> 3;
  const int flat = blockIdx.x;
  const int sw = (flat & 7) * cpx + (flat >> 3);   // grid % 8 == 0 (bijective)
  const int bx = sw % ntn, by = sw / ntn;
  const int m0 = by * 256, n0 = bx * 256;

  const int tid = threadIdx.x;
  const int l = tid & 63, w = tid >> 6;
  const int wm = w >> 2, wn = w & 3;     // 2M x 4N
  const int lr = l & 15, kg = l >> 4;    // kg in 0..3 (col16 within BK=32)

  __shared__ alignas(16) bf16 sA[3][256 * 32];   // 48 KiB
  __shared__ alignas(16) bf16 sB[3][256 * 32];   // 48 KiB

  f32x4 acc[8][4] = {};

  // swizzled ds_read byte offsets: global col16=kg of row r
  int oA[8], oB[4];
#pragma unroll
  for (int i = 0; i < 8; ++i) {
    int r = wm * 128 + i * 16 + lr;
    oA[i] = (r * 4 + (kg ^ ((r >> 1) & 3))) * 16;
  }
#pragma unroll
  for (int j = 0; j < 4; ++j) {
    int r = wn * 64 + j * 16 + lr;
    oB[j] = (r * 4 + (kg ^ ((r >> 1) & 3))) * 16;
  }

  auto stageA = [&](int sp, int kt, int half) {
    int u = half * 512 + tid;
    int prow = u >> 2, ps = u & 3;
    int lc = ps ^ ((prow >> 1) & 3);              // inverse swizzle on source
    gload_lds16(A + (size_t)(m0 + prow) * K + kt * 32 + lc * 8,
                &sA[sp][(half * 512 + w * 64) * 8]);
  };
  auto stageB = [&](int sp, int kt, int half) {
    int u = half * 512 + tid;
    int prow = u >> 2, ps = u & 3;
    int lc = ps ^ ((prow >> 1) & 3);
    gload_lds16(BT + (size_t)(n0 + prow) * K + kt * 32 + lc * 8,
                &sB[sp][(half * 512 + w * 64) * 8]);
  };

  // prologue: tiles 0,1 (8 gloads); tile 0 resident (tile 1's 4 in flight)
#pragma unroll
  for (int tt = 0; tt < 2; ++tt) {
    stageA(tt, tt, 0); stageB(tt, tt, 0);
    stageA(tt, tt, 1); stageB(tt, tt, 1);
  }
  asm volatile("s_waitcnt vmcnt(4)\n\ts_barrier" ::: "memory");

  for (int t = 0; t < KT; ++t) {
    const int s = t % 3, sp = (t + 2) % 3;
    const int tpc = (t + 2 < KT) ? t + 2 : t;    // dummy tail: uniform ledger
    const char* bA = (const char*)&sA[s][0];
    const char* bB = (const char*)&sB[s][0];

    bf16x8 af[8], bfr[4];
#pragma unroll
    for (int i = 0; i < 8; ++i) af[i] = *(const bf16x8*)(bA + oA[i]);
#pragma unroll
    for (int j = 0; j < 4; ++j) bfr[j] = *(const bf16x8*)(bB + oB[j]);

    stageA(sp, tpc, 0); stageB(sp, tpc, 0);
    stageA(sp, tpc, 1); stageB(sp, tpc, 1);

    __builtin_amdgcn_s_setprio(1);
#pragma unroll
    for (int i = 0; i < 8; ++i)
#pragma unroll
      for (int j = 0; j < 4; ++j)
        acc[i][j] = mfma16(af[i], bfr[j], acc[i][j]);
    __builtin_amdgcn_s_setprio(0);

    asm volatile("s_waitcnt vmcnt(4)\n\ts_barrier" ::: "memory");
  }
  asm volatile("s_waitcnt vmcnt(0)" ::: "memory");     // drain tail dummies

  // ---- epilogue ----
  const int cb = n0 >> 10;          // uniform per block (256 | 1024)
#pragma unroll
  for (int i = 0; i < 8; ++i) {
#pragma unroll
    for (int jj = 0; jj < 4; ++jj) {
      const int n = n0 + wn * 64 + jj * 16 + lr;
      const int m0r = m0 + wm * 128 + i * 16 + kg * 4;
      if (MODE == 0) {
        const int nn = n & 1023;
        if (cb == 0) {
          const float b_ = bias0[nn];
#pragma unroll
          for (int r = 0; r < 4; ++r)
            Qo[(size_t)(m0r + r) * ADIM + nn] = (bf16)(acc[i][jj][r] + b_);
        } else if (cb == 1) {
          const float b_ = bias1[nn];
#pragma unroll
          for (int r = 0; r < 4; ++r) {
            float v = acc[i][jj][r] + b_;
            Ko[(size_t)(m0r + r) * ADIM + nn] = (bf16)(v > 0.f ? v + 1.f : __expf(v));
          }
        } else {
          const float b_ = bias2[nn];
          const int bb = m0r >> 11, t0c = m0r & 2047;
          bf16x4 pk;
#pragma unroll
          for (int r = 0; r < 4; ++r) pk[r] = (bf16)(acc[i][jj][r] + b_);
          *(bf16x4*)&Vto[((size_t)bb * ADIM + nn) * ASEQ + t0c] = pk;
        }
      } else {
        const float b_ = bias0[n];
#pragma unroll
        for (int r = 0; r < 4; ++r)
          outF[(size_t)(m0r + r) * ADIM + n] = acc[i][jj][r] + b_;
      }
    }
  }
}

// --------- windowed decay attention: one (batch, 64-row q-tile) per WG ---------
__global__ __launch_bounds__(256) void k_attn(
    const bf16* __restrict__ Qg, const bf16* __restrict__ Kg,
    const bf16* __restrict__ Vt, bf16* __restrict__ Rb,
    const float* __restrict__ decay_param)
{
  const int b = blockIdx.y;
  const int T0 = blockIdx.x * 64;
  const int tid = threadIdx.x;
  const int l = tid & 63, w = tid >> 6;
  const int lr = l & 15, lk = (l >> 4) * 8;

  const float dp = decay_param[0];
  const float decay = 1.f / (1.f + __expf(-dp));
  const float l2d = __log2f(decay);

  __shared__ alignas(16) bf16 lQ[2][64 * 32];
  __shared__ alignas(16) bf16 lK[2][128 * 32];
  __shared__ alignas(16) bf16 lV[2][128 * 32];
  __shared__ alignas(16) bf16 lP[64 * 136];

  const bf16* Qb = Qg + (size_t)(b * ASEQ + T0) * ADIM;

  auto stageQK = [&](int buf, int k0) {
    {
      const bf16* g = Qb + (size_t)(w * 16 + (l >> 2)) * ADIM + k0 + (l & 3) * 8;
      gload_lds16(g, &lQ[buf][w * 16 * 32]);
    }
#pragma unroll
    for (int cc = 0; cc < 2; ++cc) {
      int c = 2 * w + cc;
      int sg = T0 - 64 + c * 16 + (l >> 2);
      if (sg < 0) sg = 0;
      const bf16* g = Kg + (size_t)(b * ASEQ + sg) * ADIM + k0 + (l & 3) * 8;
      gload_lds16(g, &lK[buf][c * 16 * 32]);
    }
  };

  f32x4 sc[4][2] = {};
  stageQK(0, 0);
  __syncthreads();
  for (int kt = 0; kt < 32; ++kt) {
    int cur = kt & 1;
    if (kt + 1 < 32) stageQK(cur ^ 1, (kt + 1) * 32);
    bf16x8 af[4], bfr[2];
#pragma unroll
    for (int i = 0; i < 4; ++i)
      af[i] = *(const bf16x8*)&lQ[cur][(i * 16 + lr) * 32 + lk];
#pragma unroll
    for (int j = 0; j < 2; ++j)
      bfr[j] = *(const bf16x8*)&lK[cur][(w * 32 + j * 16 + lr) * 32 + lk];
#pragma unroll
    for (int i = 0; i < 4; ++i)
#pragma unroll
      for (int j = 0; j < 2; ++j)
        sc[i][j] = mfma16(af[i], bfr[j], sc[i][j]);
    __syncthreads();
  }

  const int er = (l >> 4) * 4, ec = l & 15;
#pragma unroll
  for (int i = 0; i < 4; ++i)
#pragma unroll
    for (int j = 0; j < 2; ++j)
#pragma unroll
      for (int r = 0; r < 4; ++r) {
        int tl = i * 16 + er + r;
        int sl = w * 32 + j * 16 + ec;
        int sg = T0 - 64 + sl;
        int delta = (T0 + tl) - 1 - sg;
        float wgt = (delta >= 0 && delta < 64 && sg >= 0)
                        ? exp2f((float)delta * l2d) : 0.f;
        lP[tl * 136 + sl] = (bf16)(sc[i][j][r] * wgt);
      }

  auto stageV = [&](int buf, int g) {
    int nc = g >> 2, ks = g & 3;
#pragma unroll
    for (int cc = 0; cc < 2; ++cc) {
      int c = 2 * w + cc;
      int drow = nc * 128 + c * 16 + (l >> 2);
      int scol = T0 - 64 + ks * 32 + (l & 3) * 8;
      if (scol < 0) scol = 0;
      const bf16* gv = Vt + ((size_t)b * ADIM + drow) * ASEQ + scol;
      gload_lds16(gv, &lV[buf][c * 16 * 32]);
    }
  };

  f32x4 o[4][2] = {};
  stageV(0, 0);
  __syncthreads();

  for (int g = 0; g < 32; ++g) {
    int cur = g & 1;
    if (g + 1 < 32) stageV(cur ^ 1, g + 1);
    int nc = g >> 2, ks = g & 3;
    bf16x8 af[4], bfr[2];
#pragma unroll
    for (int i = 0; i < 4; ++i)
      af[i] = *(const bf16x8*)&lP[(i * 16 + lr) * 136 + ks * 32 + lk];
#pragma unroll
    for (int j = 0; j < 2; ++j)
      bfr[j] = *(const bf16x8*)&lV[cur][(w * 32 + j * 16 + lr) * 32 + lk];
#pragma unroll
    for (int i = 0; i < 4; ++i)
#pragma unroll
      for (int j = 0; j < 2; ++j)
        o[i][j] = mfma16(af[i], bfr[j], o[i][j]);
    if (ks == 3) {
#pragma unroll
      for (int i = 0; i < 4; ++i)
#pragma unroll
        for (int j = 0; j < 2; ++j) {
#pragma unroll
          for (int r = 0; r < 4; ++r) {
            int tl = i * 16 + er + r;
            int dl = nc * 128 + w * 32 + j * 16 + ec;
            Rb[(size_t)(b * ASEQ + T0 + tl) * ADIM + dl] = (bf16)o[i][j][r];
          }
#pragma unroll
          for (int r = 0; r < 4; ++r) o[i][j][r] = 0.f;
        }
    }
    __syncthreads();
  }
}

extern "C" void kernel_launch(void* const* d_in, const int* in_sizes, int n_in,
                              void* d_out, int out_size, void* d_ws, size_t ws_size,
                              hipStream_t stream) {
  const float* x  = (const float*)d_in[0];
  const float* Wq = (const float*)d_in[1];
  const float* bq = (const float*)d_in[2];
  const float* Wk = (const float*)d_in[3];
  const float* bk = (const float*)d_in[4];
  const float* Wv = (const float*)d_in[5];
  const float* bv = (const float*)d_in[6];
  const float* Wo = (const float*)d_in[7];
  const float* bo = (const float*)d_in[8];
  const float* dp = (const float*)d_in[9];
  float* out = (float*)d_out;

  char* ws = (char*)d_ws;
  bf16* Xb  = (bf16*)(ws + ((size_t)0 << 20));    // [16384][1024]
  bf16* Qb  = (bf16*)(ws + ((size_t)32 << 20));
  bf16* Kb  = (bf16*)(ws + ((size_t)64 << 20));
  bf16* Vtb = (bf16*)(ws + ((size_t)96 << 20));   // [8][1024][2048]
  bf16* Rbb = (bf16*)(ws + ((size_t)128 << 20));
  bf16* WcT = (bf16*)(ws + ((size_t)160 << 20));  // [3072][1024]
  bf16* WoT = (bf16*)(ws + ((size_t)166 << 20));  // [1024][1024]

  const int M = ABATCH * ASEQ;  // 16384

  k_cast_x<<<2048, 256, 0, stream>>>(x, Xb, (M * ADIM) / 4);
  k_prep_w_t<<<1024, 256, 0, stream>>>(Wq, Wk, Wv, Wo, WcT, WoT);
  k_gemm2x<0><<<768, 512, 0, stream>>>(
      Xb, WcT, bq, bk, bv, Qb, Kb, Vtb, nullptr, 12);
  k_attn<<<dim3(32, 8), 256, 0, stream>>>(Qb, Kb, Vtb, Rbb, dp);
  k_gemm2x<1><<<256, 512, 0, stream>>>(
      Rbb, WoT, bo, nullptr, nullptr, nullptr, nullptr, nullptr, out, 4);
}